// Round 13
// baseline (360.222 us; speedup 1.0000x reference)
//
#include <hip/hip_runtime.h>
#include <hip/hip_bf16.h>
#include <cstdint>

#define DEVINL __device__ __forceinline__
typedef unsigned long long ull;

// ---------------------------------------------------------------------------
// 2-layer GCN (gcn_norm w/ self-loops) -> per-pair MLP -> per-graph softmax.
// R13: k_gather 4-deep neighbor unroll (4 independent accumulator sets,
// int4 pk loads). R12 left the two gathers as the largest sub-cutoff stages;
// their 2-deep unroll keeps only 2 random-row loads in flight per lane while
// row latency (~600-900cyc) x degree(~10) dominates. Everything else
// byte-identical to R12 (interleaved hist⊕gemm1, MFMA gemms/edge, bf16
// tables, atomic-free fill, 64-bit packed histogram).
// ---------------------------------------------------------------------------

typedef __attribute__((ext_vector_type(8))) short bf16x8;
typedef __attribute__((ext_vector_type(4))) float f32x4;

DEVINL float bflo(unsigned u) { return __uint_as_float(u << 16); }
DEVINL float bfhi(unsigned u) { return __uint_as_float(u & 0xffff0000u); }
DEVINL unsigned packbf2(float a, float b) {   // RNE pack of 2 fp32 -> 2 bf16
  unsigned ua = __float_as_uint(a); ua = (ua + 0x7fff + ((ua >> 16) & 1)) >> 16;
  unsigned ub = __float_as_uint(b); ub = (ub + 0x7fff + ((ub >> 16) & 1)) >> 16;
  return ua | (ub << 16);
}
DEVINL unsigned short packbf1(float a) {
  unsigned ua = __float_as_uint(a);
  return (unsigned short)((ua + 0x7fff + ((ua >> 16) & 1)) >> 16);
}

// ---------- weight folding ----------
__global__ void k_prep(const float* __restrict__ Wp, const float* __restrict__ bp,
                       const float* __restrict__ W1,
                       const float* __restrict__ W2, const float* __restrict__ Wa,
                       const float* __restrict__ ba, const float* __restrict__ b2,
                       const float* __restrict__ Wb,
                       unsigned short* __restrict__ WfuseF, float* __restrict__ bfuse,
                       unsigned short* __restrict__ McatF, float* __restrict__ bU,
                       unsigned short* __restrict__ WbF) {
  int id = blockIdx.x * 256 + threadIdx.x;
  if (id < 8192) {                      // WfuseF = pack(Wp@W1), B-frag layout
    int j = id & 7, q = id >> 3;
    int l = q & 63, p = q >> 6;
    int nt = p & 7, kci = p >> 3;
    int kr = kci * 32 + ((l >> 4) << 3) + j;
    int nc = nt * 16 + (l & 15);
    float s = 0.f;
    for (int c = 0; c < 128; c++) s = fmaf(Wp[kr * 128 + c], W1[c * 128 + nc], s);
    WfuseF[id] = packbf1(s);
  } else if (id < 8320) {               // bfuse = bp@W1
    int j = id - 8192;
    float s = 0.f;
    for (int c = 0; c < 128; c++) s = fmaf(bp[c], W1[c * 128 + j], s);
    bfuse[j] = s;
  } else if (id < 24704) {              // McatF = pack([W2@Wa0 | W2@Wa1])
    int m = id - 8320;
    int j8 = m & 7, q = m >> 3;
    int l = q & 63, p = q >> 6;
    int nt = p & 7, kci = p >> 3;
    int kr = kci * 32 + ((l >> 4) << 3) + j8;
    int nc = nt * 16 + (l & 15);
    int jj = nc & 63, koff = (nc < 64) ? 0 : 64;
    float s = 0.f;
    for (int k = 0; k < 64; k++) s = fmaf(W2[kr * 64 + k], Wa[(koff + k) * 64 + jj], s);
    McatF[m] = packbf1(s);
  } else if (id < 24832) {              // bU = [b2@Wa0+ba | b2@Wa1]
    int j = id - 24704;
    int jj = j & 63, koff = (j < 64) ? 0 : 64;
    float s = (j < 64) ? ba[j] : 0.f;
    for (int k = 0; k < 64; k++) s = fmaf(b2[k], Wa[(koff + k) * 64 + jj], s);
    bU[j] = s;
  } else if (id < 24832 + 2048) {       // WbF bf16 B-fragment pack (k_edge)
    int m = id - 24832;
    int j = m & 7;
    int idx = m >> 3;
    int nt = idx & 1, kt = (idx >> 1) & 1, l = idx >> 2;
    int kr = kt * 32 + ((l >> 4) << 3) + j;
    int nc = nt * 16 + (l & 15);
    WbF[m] = packbf1(Wb[kr * 32 + nc]);
  }
}

// ---------- fused: CSR histogram (atomic-bound) ⊕ gemm1 (MFMA), INTERLEAVED ----
__global__ __launch_bounds__(256) void k_histgemm(
    const int* __restrict__ col, const float* __restrict__ w,
    ull* __restrict__ cnt64, int* __restrict__ pos, int E, int gG,
    const float* __restrict__ x, const unsigned short* __restrict__ WF,
    const float* __restrict__ bias, unsigned short* __restrict__ C, int N) {
  __shared__ alignas(16) unsigned short sA[128 * 40];
  const int bid = blockIdx.x;
  const int ilv = gG * 5;
  int hb = -1, gb = -1;
  if (bid < ilv) {
    if ((bid % 5) == 4) gb = bid / 5;
    else hb = bid - bid / 5;
  } else {
    hb = bid - gG;
  }
  if (hb >= 0) {   // ---- hist body ----
    int e = hb * 256 + threadIdx.x;
    if (e < E) {
      ull inc = (1ULL << 36) | (ull)(unsigned)(w[e] * 268435456.0f + 0.5f);
      ull old = atomicAdd(&cnt64[col[e]], inc);
      pos[e] = (int)(old >> 36);
    }
    return;
  }
  // ---- gemm1 body (K=64, A fp32, bias, C bf16) ----
  const int t = threadIdx.x;
  const int lane = t & 63, wave = t >> 6;
  const int quad = lane >> 4, n0 = lane & 15;
  const int r0 = gb * 128;
  f32x4 acc[8][2] = {};
  for (int kc = 0; kc < 64; kc += 32) {
    __syncthreads();
#pragma unroll
    for (int i = 0; i < 4; i++) {
      int idx = (t + i * 256) * 4;
      int r = idx >> 5, k = idx & 31;
      int gr = r0 + r;
      float4 v = make_float4(0.f, 0.f, 0.f, 0.f);
      if (gr < N) v = *(const float4*)&x[(size_t)gr * 64 + kc + k];
      uint2 pv;
      pv.x = packbf2(v.x, v.y);
      pv.y = packbf2(v.z, v.w);
      *(uint2*)&sA[r * 40 + k] = pv;
    }
    __syncthreads();
    const int kci = kc >> 5;
    const bf16x8* wf = (const bf16x8*)WF;
    bf16x8 b0 = wf[(kci * 8 + wave * 2 + 0) * 64 + lane];
    bf16x8 b1 = wf[(kci * 8 + wave * 2 + 1) * 64 + lane];
#pragma unroll
    for (int rt = 0; rt < 8; rt++) {
      bf16x8 af = *(const bf16x8*)&sA[(rt * 16 + n0) * 40 + quad * 8];
      acc[rt][0] = __builtin_amdgcn_mfma_f32_16x16x32_bf16(af, b0, acc[rt][0], 0, 0, 0);
      acc[rt][1] = __builtin_amdgcn_mfma_f32_16x16x32_bf16(af, b1, acc[rt][1], 0, 0, 0);
    }
  }
  const int colbase = wave * 32;
  const float bc0 = bias[colbase + n0];
  const float bc1 = bias[colbase + 16 + n0];
#pragma unroll
  for (int rt = 0; rt < 8; rt++) {
#pragma unroll
    for (int reg = 0; reg < 4; reg++) {
      int r = r0 + rt * 16 + quad * 4 + reg;
      if (r < N) {
        unsigned short* cp = C + (size_t)r * 128 + colbase;
        cp[n0] = packbf1(acc[rt][0][reg] + bc0);
        cp[n0 + 16] = packbf1(acc[rt][1][reg] + bc1);
      }
    }
  }
}

__global__ void k_scan1(const ull* __restrict__ cnt64, int* __restrict__ start,
                        int* __restrict__ bsum, int N) {
  __shared__ int s[256];
  int t = threadIdx.x;
  int i = blockIdx.x * 256 + t;
  int v = (i < N) ? (int)(cnt64[i] >> 36) : 0;
  s[t] = v; __syncthreads();
  int x = v;
#pragma unroll
  for (int off = 1; off < 256; off <<= 1) {
    int y = (t >= off) ? s[t - off] : 0;
    __syncthreads();
    x += y; s[t] = x;
    __syncthreads();
  }
  if (i < N) start[i] = x - v;   // block-local exclusive
  if (t == 255) bsum[blockIdx.x] = x;
}
__global__ void k_scan2(const int* __restrict__ bsum, int* __restrict__ boff,
                        int nb, int* __restrict__ startN) {
  __shared__ int s[512];
  int t = threadIdx.x;
  int v = (t < nb) ? bsum[t] : 0;
  s[t] = v; __syncthreads();
  int x = v;
#pragma unroll
  for (int off = 1; off < 512; off <<= 1) {
    int y = (t >= off) ? s[t - off] : 0;
    __syncthreads();
    x += y; s[t] = x;
    __syncthreads();
  }
  if (t < nb) boff[t] = x - v;
  if (t == nb - 1) *startN = x;  // = E
}
__global__ void k_scan3dinv(int* __restrict__ start, const int* __restrict__ boff,
                            const ull* __restrict__ cnt64, float* __restrict__ dinv, int N) {
  int i = blockIdx.x * 256 + threadIdx.x;
  if (i < N) {
    start[i] += boff[blockIdx.x];
    float sw = (float)(cnt64[i] & 0xFFFFFFFFFULL) * 3.7252903e-09f;  // *2^-28
    dinv[i] = rsqrtf(1.0f + sw);
  }
}

// ---------- atomic-free CSR fill ----------
__global__ void k_fill(const int* __restrict__ row, const int* __restrict__ col,
                       const float* __restrict__ w, const float* __restrict__ dinv,
                       const int* __restrict__ start, const int* __restrict__ pos,
                       int2* __restrict__ pk, int E) {
  int e = blockIdx.x * 256 + threadIdx.x;
  if (e >= E) return;
  int r = row[e];
  int p = start[col[e]] + pos[e];
  pk[p] = make_int2(r, __float_as_int(w[e] * dinv[r]));
}

// ---------- MFMA bf16 GEMM (gemm2): C[N,128] = A[N,128] @ W (A bf16) ----------
template<int K, bool ABF, bool BIAS>
__global__ __launch_bounds__(256) void k_gemm_mfma(const void* __restrict__ Av,
    const unsigned short* __restrict__ WF, const float* __restrict__ bias,
    unsigned short* __restrict__ C, int N) {
  __shared__ alignas(16) unsigned short sA[128 * 40];
  const int t = threadIdx.x;
  const int lane = t & 63, wave = t >> 6;
  const int quad = lane >> 4, n0 = lane & 15;
  const int r0 = blockIdx.x * 128;
  f32x4 acc[8][2] = {};
  for (int kc = 0; kc < K; kc += 32) {
    __syncthreads();
    if (ABF) {
      const unsigned short* Ab = (const unsigned short*)Av;
#pragma unroll
      for (int i = 0; i < 2; i++) {
        int idx = (t + i * 256) * 8;
        int r = idx >> 5, k = idx & 31;
        int gr = r0 + r;
        uint4 v = make_uint4(0u, 0u, 0u, 0u);
        if (gr < N) v = *(const uint4*)&Ab[(size_t)gr * K + kc + k];
        *(uint4*)&sA[r * 40 + k] = v;
      }
    } else {
      const float* Af = (const float*)Av;
#pragma unroll
      for (int i = 0; i < 4; i++) {
        int idx = (t + i * 256) * 4;
        int r = idx >> 5, k = idx & 31;
        int gr = r0 + r;
        float4 v = make_float4(0.f, 0.f, 0.f, 0.f);
        if (gr < N) v = *(const float4*)&Af[(size_t)gr * K + kc + k];
        uint2 pv;
        pv.x = packbf2(v.x, v.y);
        pv.y = packbf2(v.z, v.w);
        *(uint2*)&sA[r * 40 + k] = pv;
      }
    }
    __syncthreads();
    const int kci = kc >> 5;
    const bf16x8* wf = (const bf16x8*)WF;
    bf16x8 b0 = wf[(kci * 8 + wave * 2 + 0) * 64 + lane];
    bf16x8 b1 = wf[(kci * 8 + wave * 2 + 1) * 64 + lane];
#pragma unroll
    for (int rt = 0; rt < 8; rt++) {
      bf16x8 af = *(const bf16x8*)&sA[(rt * 16 + n0) * 40 + quad * 8];
      acc[rt][0] = __builtin_amdgcn_mfma_f32_16x16x32_bf16(af, b0, acc[rt][0], 0, 0, 0);
      acc[rt][1] = __builtin_amdgcn_mfma_f32_16x16x32_bf16(af, b1, acc[rt][1], 0, 0, 0);
    }
  }
  const int colbase = wave * 32;
  const float bc0 = BIAS ? bias[colbase + n0] : 0.f;
  const float bc1 = BIAS ? bias[colbase + 16 + n0] : 0.f;
#pragma unroll
  for (int rt = 0; rt < 8; rt++) {
#pragma unroll
    for (int reg = 0; reg < 4; reg++) {
      int r = r0 + rt * 16 + quad * 4 + reg;
      if (r < N) {
        unsigned short* cp = C + (size_t)r * 128 + colbase;
        cp[n0] = packbf1(acc[rt][0][reg] + bc0);
        cp[n0 + 16] = packbf1(acc[rt][1][reg] + bc1);
      }
    }
  }
}

// ---------- CSR gather (bf16 table), 4-deep unroll (R13) ----------
// 16 lanes/node, lane owns 8 bf16 cols. 4 independent accumulator sets keep
// 4 random-row loads in flight per lane; pk read as int4 (2 neighbors/load).
template<bool RELU, bool OUTBF>
__global__ __launch_bounds__(256) void k_gather(const int* __restrict__ start,
                         const int2* __restrict__ pk,
                         const unsigned short* __restrict__ hw, const float* __restrict__ dinv,
                         const float* __restrict__ bias, void* __restrict__ hout, int N) {
  const int t = threadIdx.x;
  const int v = blockIdx.x * 16 + (t >> 4);
  if (v >= N) return;
  const int j8 = (t & 15) * 8;
  const int b = start[v];
  const int en = start[v + 1];
  float a0[8] = {}, a1[8] = {}, a2[8] = {}, a3[8] = {};
  int i = b;
  for (; i + 3 < en; i += 4) {
    int4 pa = *(const int4*)&pk[i];       // neighbors i, i+1
    int4 pb = *(const int4*)&pk[i + 2];   // neighbors i+2, i+3
    float n0 = __int_as_float(pa.y), n1 = __int_as_float(pa.w);
    float n2 = __int_as_float(pb.y), n3 = __int_as_float(pb.w);
    uint4 w0 = *(const uint4*)&hw[(size_t)pa.x * 128 + j8];
    uint4 w1 = *(const uint4*)&hw[(size_t)pa.z * 128 + j8];
    uint4 w2 = *(const uint4*)&hw[(size_t)pb.x * 128 + j8];
    uint4 w3 = *(const uint4*)&hw[(size_t)pb.z * 128 + j8];
    a0[0] = fmaf(n0, bflo(w0.x), a0[0]); a0[1] = fmaf(n0, bfhi(w0.x), a0[1]);
    a0[2] = fmaf(n0, bflo(w0.y), a0[2]); a0[3] = fmaf(n0, bfhi(w0.y), a0[3]);
    a0[4] = fmaf(n0, bflo(w0.z), a0[4]); a0[5] = fmaf(n0, bfhi(w0.z), a0[5]);
    a0[6] = fmaf(n0, bflo(w0.w), a0[6]); a0[7] = fmaf(n0, bfhi(w0.w), a0[7]);
    a1[0] = fmaf(n1, bflo(w1.x), a1[0]); a1[1] = fmaf(n1, bfhi(w1.x), a1[1]);
    a1[2] = fmaf(n1, bflo(w1.y), a1[2]); a1[3] = fmaf(n1, bfhi(w1.y), a1[3]);
    a1[4] = fmaf(n1, bflo(w1.z), a1[4]); a1[5] = fmaf(n1, bfhi(w1.z), a1[5]);
    a1[6] = fmaf(n1, bflo(w1.w), a1[6]); a1[7] = fmaf(n1, bfhi(w1.w), a1[7]);
    a2[0] = fmaf(n2, bflo(w2.x), a2[0]); a2[1] = fmaf(n2, bfhi(w2.x), a2[1]);
    a2[2] = fmaf(n2, bflo(w2.y), a2[2]); a2[3] = fmaf(n2, bfhi(w2.y), a2[3]);
    a2[4] = fmaf(n2, bflo(w2.z), a2[4]); a2[5] = fmaf(n2, bfhi(w2.z), a2[5]);
    a2[6] = fmaf(n2, bflo(w2.w), a2[6]); a2[7] = fmaf(n2, bfhi(w2.w), a2[7]);
    a3[0] = fmaf(n3, bflo(w3.x), a3[0]); a3[1] = fmaf(n3, bfhi(w3.x), a3[1]);
    a3[2] = fmaf(n3, bflo(w3.y), a3[2]); a3[3] = fmaf(n3, bfhi(w3.y), a3[3]);
    a3[4] = fmaf(n3, bflo(w3.z), a3[4]); a3[5] = fmaf(n3, bfhi(w3.z), a3[5]);
    a3[6] = fmaf(n3, bflo(w3.w), a3[6]); a3[7] = fmaf(n3, bfhi(w3.w), a3[7]);
  }
  for (; i < en; i++) {
    int2 q = pk[i];
    float n = __int_as_float(q.y);
    uint4 w0 = *(const uint4*)&hw[(size_t)q.x * 128 + j8];
    a0[0] = fmaf(n, bflo(w0.x), a0[0]); a0[1] = fmaf(n, bfhi(w0.x), a0[1]);
    a0[2] = fmaf(n, bflo(w0.y), a0[2]); a0[3] = fmaf(n, bfhi(w0.y), a0[3]);
    a0[4] = fmaf(n, bflo(w0.z), a0[4]); a0[5] = fmaf(n, bfhi(w0.z), a0[5]);
    a0[6] = fmaf(n, bflo(w0.w), a0[6]); a0[7] = fmaf(n, bfhi(w0.w), a0[7]);
  }
  const float d = dinv[v];
  const float s = d * d;
  uint4 wv = *(const uint4*)&hw[(size_t)v * 128 + j8];
  float hv[8] = { bflo(wv.x), bfhi(wv.x), bflo(wv.y), bfhi(wv.y),
                  bflo(wv.z), bfhi(wv.z), bflo(wv.w), bfhi(wv.w) };
  float4 bv0 = *(const float4*)&bias[j8];
  float4 bv1 = *(const float4*)&bias[j8 + 4];
  float bvv[8] = { bv0.x, bv0.y, bv0.z, bv0.w, bv1.x, bv1.y, bv1.z, bv1.w };
  float o[8];
#pragma unroll
  for (int k = 0; k < 8; k++) {
    float a = (a0[k] + a1[k]) + (a2[k] + a3[k]);
    o[k] = fmaf(d, a, fmaf(s, hv[k], bvv[k]));
    if (RELU) o[k] = fmaxf(o[k], 0.f);
  }
  if (OUTBF) {
    uint4 pv;
    pv.x = packbf2(o[0], o[1]); pv.y = packbf2(o[2], o[3]);
    pv.z = packbf2(o[4], o[5]); pv.w = packbf2(o[6], o[7]);
    *(uint4*)&((unsigned short*)hout)[(size_t)v * 128 + j8] = pv;
  } else {
    float* hf = (float*)hout;
    *(float4*)&hf[(size_t)v * 128 + j8]     = make_float4(o[0], o[1], o[2], o[3]);
    *(float4*)&hf[(size_t)v * 128 + j8 + 4] = make_float4(o[4], o[5], o[6], o[7]);
  }
}

// ---------- per-edge kernel (MFMA layer b) ----------
__global__ __launch_bounds__(256) void k_edge(const unsigned short* __restrict__ U,
    const int* __restrict__ p0, const int* __restrict__ p1,
    const unsigned short* __restrict__ WbF, const float* __restrict__ bb,
    const float* __restrict__ Wc, const float* __restrict__ bc,
    float* __restrict__ logits, int ES) {
  __shared__ alignas(16) unsigned short sS1[64 * 72];   // bf16 [edge][k], stride 72
  const int t = threadIdx.x;
  const int base = blockIdx.x << 6;
  {  // gather + add + relu + bf16-pack -> sS1
    int p = t >> 2, q = t & 3;
    int e = base + p; if (e >= ES) e = ES - 1;
    const unsigned short* r0 = U + (size_t)p0[e] * 128;        // U0: cols 0..63
    const unsigned short* r1 = U + (size_t)p1[e] * 128 + 64;   // U1: cols 64..127
#pragma unroll
    for (int i = 0; i < 4; i++) {
      int c = i * 16 + q * 4;
      uint2 av = *(const uint2*)&r0[c];
      uint2 bv = *(const uint2*)&r1[c];
      float ox = fmaxf(bflo(av.x) + bflo(bv.x), 0.f);
      float oy = fmaxf(bfhi(av.x) + bfhi(bv.x), 0.f);
      float oz = fmaxf(bflo(av.y) + bflo(bv.y), 0.f);
      float ow = fmaxf(bfhi(av.y) + bfhi(bv.y), 0.f);
      uint2 pv;
      pv.x = packbf2(ox, oy);
      pv.y = packbf2(oz, ow);
      *(uint2*)&sS1[p * 72 + c] = pv;
    }
  }
  __syncthreads();
  const int lane = t & 63;
  const int wave = t >> 6;
  const int quad = lane >> 4, n0 = lane & 15;
  const int edge0 = wave * 16;
  bf16x8 a0 = *(const bf16x8*)&sS1[(edge0 + n0) * 72 + quad * 8];
  bf16x8 a1 = *(const bf16x8*)&sS1[(edge0 + n0) * 72 + 32 + quad * 8];
  const bf16x8* wf = (const bf16x8*)WbF;
  bf16x8 b00 = wf[lane * 4 + 0];
  bf16x8 b01 = wf[lane * 4 + 1];
  bf16x8 b10 = wf[lane * 4 + 2];
  bf16x8 b11 = wf[lane * 4 + 3];
  f32x4 acc0 = {0.f, 0.f, 0.f, 0.f};
  f32x4 acc1 = {0.f, 0.f, 0.f, 0.f};
  acc0 = __builtin_amdgcn_mfma_f32_16x16x32_bf16(a0, b00, acc0, 0, 0, 0);
  acc0 = __builtin_amdgcn_mfma_f32_16x16x32_bf16(a1, b10, acc0, 0, 0, 0);
  acc1 = __builtin_amdgcn_mfma_f32_16x16x32_bf16(a0, b01, acc1, 0, 0, 0);
  acc1 = __builtin_amdgcn_mfma_f32_16x16x32_bf16(a1, b11, acc1, 0, 0, 0);
  const float bb0 = bb[n0], bb1 = bb[n0 + 16];
  const float wc0 = Wc[n0], wc1 = Wc[n0 + 16];
  const float bcv = bc[0];
#pragma unroll
  for (int reg = 0; reg < 4; reg++) {
    float s = fmaf(fmaxf(acc0[reg] + bb0, 0.f), wc0,
                   fmaxf(acc1[reg] + bb1, 0.f) * wc1);
    s += __shfl_xor(s, 1);
    s += __shfl_xor(s, 2);
    s += __shfl_xor(s, 4);
    s += __shfl_xor(s, 8);
    if (n0 == 0) {
      int e = base + edge0 + quad * 4 + reg;
      if (e < ES) logits[e] = s + bcv;
    }
  }
}

// ---------- fused per-graph softmax: one block per graph (eg sorted) ----------
DEVINL int lbound(const int* __restrict__ a, int n, int key) {
  int lo = 0, hi = n;
  while (lo < hi) { int mid = (lo + hi) >> 1; if (a[mid] < key) lo = mid + 1; else hi = mid; }
  return lo;
}
__global__ __launch_bounds__(512) void k_softmax(const float* __restrict__ logits,
                          const int* __restrict__ eg,
                          float* __restrict__ out, int ES) {
  const int g = blockIdx.x;
  const int t = threadIdx.x;
  const int lo = lbound(eg, ES, g);
  const int hi = lbound(eg, ES, g + 1);
  if (lo >= hi) return;
  __shared__ float red[512];
  __shared__ float s_m, s_z;
  float m = -3.4e38f;
  for (int i = lo + t; i < hi; i += 512) m = fmaxf(m, logits[i]);
  red[t] = m; __syncthreads();
#pragma unroll
  for (int off = 256; off >= 1; off >>= 1) {
    if (t < off) red[t] = fmaxf(red[t], red[t + off]);
    __syncthreads();
  }
  if (t == 0) s_m = red[0];
  __syncthreads();
  const float gm = s_m;
  float z = 0.f;
  for (int i = lo + t; i < hi; i += 512) {
    float e = expf(logits[i] - gm);
    out[i] = e;
    z += e;
  }
  red[t] = z; __syncthreads();
#pragma unroll
  for (int off = 256; off >= 1; off >>= 1) {
    if (t < off) red[t] += red[t + off];
    __syncthreads();
  }
  if (t == 0) s_z = red[0];
  __syncthreads();
  const float inv = 1.0f / s_z;
  for (int i = lo + t; i < hi; i += 512) out[i] *= inv;
}

// ---------------------------------------------------------------------------
extern "C" void kernel_launch(void* const* d_in, const int* in_sizes, int n_in,
                              void* d_out, int out_size, void* d_ws, size_t ws_size,
                              hipStream_t stream) {
  const float* x  = (const float*)d_in[0];
  const int* ei   = (const int*)d_in[1];
  const float* ew = (const float*)d_in[2];
  const int* pi   = (const int*)d_in[3];
  const int* eg   = (const int*)d_in[4];
  const float* Wp = (const float*)d_in[6];
  const float* bp = (const float*)d_in[7];
  const float* W1 = (const float*)d_in[8];
  const float* b1 = (const float*)d_in[9];
  const float* W2 = (const float*)d_in[10];
  const float* b2 = (const float*)d_in[11];
  const float* Wa = (const float*)d_in[12];
  const float* ba = (const float*)d_in[13];
  const float* Wb = (const float*)d_in[14];
  const float* bb = (const float*)d_in[15];
  const float* Wc = (const float*)d_in[16];
  const float* bc = (const float*)d_in[17];

  const int N  = in_sizes[0] / 64;
  const int E  = in_sizes[2];
  const int ES = in_sizes[4];
  const int G  = 128;

  float* ws = (float*)d_ws;
  size_t o = 0;
  const size_t Npad = ((size_t)N + 31) & ~(size_t)31;
  ull* cnt64 = (ull*)(ws + o);  o += 2 * Npad;          // packed count|weightsum
  float* dinv = (float*)(ws + o); o += Npad;
  int* start = (int*)(ws + o);  o += Npad + 32;         // exclusive prefix, N+1 entries
  int* bsum = (int*)(ws + o);   o += 512;
  int* boff = (int*)(ws + o);   o += 512;
  int* pos = (int*)(ws + o);    o += ((size_t)E + 31) & ~(size_t)31;  // own buffer
  int2* pk = (int2*)(ws + o);   o += (size_t)E * 2;
  float* A = ws + o;            o += (size_t)N * 128;   // h1 bf16 -> U bf16
  float* B = ws + o;            o += (size_t)N * 128;   // hw1 bf16 -> V bf16 -> logits
  unsigned short* WfuseF = (unsigned short*)(ws + o); o += 4096;   // 8192 bf16
  float* bfuse = ws + o;        o += 128;
  unsigned short* McatF = (unsigned short*)(ws + o); o += 8192;    // 16384 bf16
  float* bU = ws + o;           o += 128;
  unsigned short* WbF = (unsigned short*)(ws + o); o += 1024;      // 2048 bf16

  unsigned short* hw1 = (unsigned short*)B;
  unsigned short* h1 = (unsigned short*)A;  // bf16 (MFMA A-operand)
  unsigned short* V = (unsigned short*)B;   // overwrites hw1 (dead after gather1)
  unsigned short* U = (unsigned short*)A;   // overwrites h1 (dead after gemm2)
  float* logits = B;                        // overwrites V (dead after gather2)

  const int* row = ei;
  const int* col = ei + E;
  const int* p0 = pi;
  const int* p1 = pi + ES;
  float* out = (float*)d_out;

  const int gE = (E + 255) / 256;     // 3907 hist/fill blocks
  const int nb = (N + 255) / 256;
  const int gRows = (N + 127) / 128;  // 782 gemm blocks
  const int gGat = (N + 15) / 16;

  // ---- weight folding (feeds gemm blocks of k_histgemm) ----
  hipMemsetAsync(cnt64, 0, Npad * sizeof(ull), stream);
  k_prep<<<105, 256, 0, stream>>>(Wp, bp, W1, W2, Wa, ba, b2, Wb,
                                  WfuseF, bfuse, McatF, bU, WbF);

  // ---- interleaved [CSR histogram ⊕ gemm1] ----
  k_histgemm<<<gE + gRows, 256, 0, stream>>>(col, ew, cnt64, pos, E, gRows,
                                             x, WfuseF, bfuse, hw1, N);

  // ---- scans ----
  k_scan1<<<nb, 256, 0, stream>>>(cnt64, start, bsum, N);
  k_scan2<<<1, 512, 0, stream>>>(bsum, boff, nb, &start[N]);
  k_scan3dinv<<<nb, 256, 0, stream>>>(start, boff, cnt64, dinv, N);

  // ---- CSR fill ----
  k_fill<<<gE, 256, 0, stream>>>(row, col, ew, dinv, start, pos, pk, E);

  // ---- rest of node pipeline ----
  k_gather<true, true><<<gGat, 256, 0, stream>>>(start, pk, hw1, dinv, b1, (void*)h1, N);
  k_gemm_mfma<128, true, false><<<gRows, 256, 0, stream>>>(h1, McatF, nullptr, V, N);
  k_gather<false, true><<<gGat, 256, 0, stream>>>(start, pk, V, dinv, bU, (void*)U, N);

  // ---- per-edge MLP (MFMA) ----
  k_edge<<<(ES + 63) / 64, 256, 0, stream>>>(U, p0, p1, WbF, bb, Wc, bc, logits, ES);

  // ---- per-graph softmax ----
  k_softmax<<<G, 512, 0, stream>>>(logits, eg, out, ES);
}